// Round 5
// baseline (69.466 us; speedup 1.0000x reference)
//
#include <hip/hip_runtime.h>
#include <hip/hip_bf16.h>

#define B_    4
#define C_    256
#define H_    180
#define W_    180
#define NBOX  64
#define HW_   (H_ * W_)
#define NPIX  (B_ * HW_)

// Block = 256 threads = 4 waves. Each block owns 64 consecutive pixels.
//   lane (tid&63)  -> pixel  (coalesced: 64 consecutive hw addresses)
//   wave (tid>>6)  -> channel chunk of 64 channels
// Each thread accumulates 0.5*(x-t)^2 and any(t!=0) over its 64 channels for
// its pixel; per-pixel totals are combined across the 4 waves in LDS, then
// wave 0 applies the mask & anynz gate, shuffle-reduces, and does one
// atomicAdd per block.
__global__ __launch_bounds__(256) void mask_feat_loss_main(
    const float* __restrict__ x,
    const float* __restrict__ t,
    const int*   __restrict__ boxes,
    float*        ws_sum,
    unsigned int* ws_cnt)
{
    const int lane = threadIdx.x & 63;
    const int wid  = threadIdx.x >> 6;
    const int p    = blockIdx.x * 64 + lane;     // pixel index, < NPIX (grid exact)

    const int b  = p / HW_;
    const int hw = p - b * HW_;
    const int h  = hw / W_;
    const int w  = hw - h * W_;

    // Box mask: inside = (h>=lt_y) & (h<rb_y) & (w>=rb_x) & (w<lt_x)
    bool mask = false;
    const int* bb = boxes + b * NBOX * 4;
    #pragma unroll 8
    for (int n = 0; n < NBOX; ++n) {
        const int ltx = bb[n * 4 + 0];
        const int lty = bb[n * 4 + 1];
        const int rbx = bb[n * 4 + 2];
        const int rby = bb[n * 4 + 3];
        mask |= ((h >= lty) & (h < rby) & (w >= rbx) & (w < ltx));
    }

    float s = 0.0f;
    int   nz = 0;
    if (mask) {
        const size_t base = ((size_t)b * C_ + wid * 64) * HW_ + hw;
        const float* xp = x + base;
        const float* tp = t + base;
        #pragma unroll 8
        for (int c = 0; c < 64; ++c) {
            const float tv = tp[(size_t)c * HW_];
            const float xv = xp[(size_t)c * HW_];
            nz |= (tv != 0.0f);                 // NaN != 0 is true (matches ref)
            const float d = xv - tv;
            float term = 0.5f * d * d;
            if (isnan(tv)) term = 0.0f;         // t = where(isnan(t), x, t)
            s += term;
        }
    }

    // Combine the 4 channel-chunks per pixel via LDS.
    __shared__ float ssum[4][64];
    __shared__ int   snz[4][64];
    ssum[wid][lane] = s;
    snz[wid][lane]  = nz;
    __syncthreads();

    if (wid == 0) {
        float s_tot  = ssum[0][lane] + ssum[1][lane] + ssum[2][lane] + ssum[3][lane];
        int   nz_tot = snz[0][lane] | snz[1][lane] | snz[2][lane] | snz[3][lane];

        float sc = (mask && nz_tot) ? s_tot : 0.0f;
        int   cc = (mask && nz_tot) ? 1 : 0;

        // Wave (64-lane) reduction
        #pragma unroll
        for (int off = 32; off > 0; off >>= 1) {
            sc += __shfl_down(sc, off, 64);
            cc += __shfl_down(cc, off, 64);
        }
        if (lane == 0) {
            if (sc != 0.0f) atomicAdd(ws_sum, sc);
            if (cc != 0)    atomicAdd(ws_cnt, (unsigned int)cc);
        }
    }
}

__global__ void mask_feat_loss_finalize(const float* ws_sum,
                                        const unsigned int* ws_cnt,
                                        float* out)
{
    const float S = ws_sum[0];
    const float n = (float)ws_cnt[0];
    // loss = S / (C * pos_norm), then / B
    out[0] = S / (n * (float)C_ * (float)B_);
}

extern "C" void kernel_launch(void* const* d_in, const int* in_sizes, int n_in,
                              void* d_out, int out_size, void* d_ws, size_t ws_size,
                              hipStream_t stream)
{
    const float* x     = (const float*)d_in[0];
    const float* t     = (const float*)d_in[1];
    const int*   boxes = (const int*)d_in[2];
    float* out = (float*)d_out;

    float*        ws_sum = (float*)d_ws;
    unsigned int* ws_cnt = (unsigned int*)((char*)d_ws + sizeof(float));

    // Zero the accumulators (ws is poisoned 0xAA and never re-poisoned).
    hipMemsetAsync(d_ws, 0, 2 * sizeof(unsigned int), stream);

    const int threads = 256;
    const int blocks  = NPIX / 64;                 // 2025, exact
    mask_feat_loss_main<<<blocks, threads, 0, stream>>>(x, t, boxes, ws_sum, ws_cnt);
    mask_feat_loss_finalize<<<1, 1, 0, stream>>>(ws_sum, ws_cnt, out);
}